// Round 4
// baseline (182.548 us; speedup 1.0000x reference)
//
#include <hip/hip_runtime.h>
#include <stdint.h>

// Input  x[b,t,h,w,c] : (4, 200, 64, 64, 8) fp32, n = h*512 + wc (wc = w*8+c)
// Output out[b,t,w,c,h]: (4, 200, 64, 8, 64) fp32
// Per neuron, per 100-step chunk: acc += x[t]; if (acc > 2) { spike=1; acc=0; }
//
// Two kernels coupled by a 4 MB bit-plane workspace (L2/L3-resident):
//  K1 spike_bits4: read-optimal. 256 blocks x 256 threads, thread = 4
//     consecutive neurons (float4 loads) -> 4 KB contiguous per (block, t).
//     Prefetch depth 8 planes (A/B groups of 4): ~8 MB concurrent footprint
//     GPU-wide (within DRAM open-row capacity) vs 16 MB at depth 16.
//  K2 expand_bits: write-optimal (proven round-0 kernel). 8 KB contiguous
//     float4 stores per (block, t); bit reads served from L2/L3.
#define HWC    32768
#define NSLAB  8
#define TTOT   200
#define CHUNK  100

// ---------------- K1: bit-packed integrate-and-fire scan (float4) ----------
__global__ __launch_bounds__(256) void spike_bits4(const float* __restrict__ x,
                                                   uint32_t* __restrict__ spk) {
    unsigned g    = blockIdx.x * 256u + threadIdx.x;   // [0, 65536)
    unsigned slab = g >> 13;                           // [0, 8)
    unsigned n0   = (g & 8191u) * 4u;                  // 4 consecutive neurons
    unsigned b    = slab >> 1, ch = slab & 1u;
    const float4* xp = (const float4*)(x + (size_t)(b * TTOT + ch * CHUNK) * HWC + n0);

    float a0 = 0.0f, a1 = 0.0f, a2 = 0.0f, a3 = 0.0f;
    uint32_t w[4][4] = {{0u,0u,0u,0u},{0u,0u,0u,0u},{0u,0u,0u,0u},{0u,0u,0u,0u}};
    float4 A[4], B[4];

#define LOAD4(V, TBASE)                                                     \
    do {                                                                    \
        _Pragma("unroll")                                                   \
        for (int k = 0; k < 4; ++k)                                         \
            V[k] = xp[(size_t)((TBASE) + k) * (HWC / 4)];                   \
    } while (0)

#define CONS4(V, TBASE)                                                     \
    do {                                                                    \
        _Pragma("unroll")                                                   \
        for (int k = 0; k < 4; ++k) {                                       \
            const int tw = (TBASE) >> 5, bb = ((TBASE) & 31) + k;           \
            a0 += V[k].x; if (a0 > 2.0f) { w[tw][0] |= (1u << bb); a0 = 0.0f; } \
            a1 += V[k].y; if (a1 > 2.0f) { w[tw][1] |= (1u << bb); a1 = 0.0f; } \
            a2 += V[k].z; if (a2 > 2.0f) { w[tw][2] |= (1u << bb); a2 = 0.0f; } \
            a3 += V[k].w; if (a3 > 2.0f) { w[tw][3] |= (1u << bb); a3 = 0.0f; } \
        }                                                                   \
    } while (0)

    LOAD4(A, 0);  LOAD4(B, 4);
    CONS4(A, 0);  LOAD4(A, 8);
    CONS4(B, 4);  LOAD4(B, 12);
    CONS4(A, 8);  LOAD4(A, 16);
    CONS4(B, 12); LOAD4(B, 20);
    CONS4(A, 16); LOAD4(A, 24);
    CONS4(B, 20); LOAD4(B, 28);
    CONS4(A, 24); LOAD4(A, 32);
    CONS4(B, 28); LOAD4(B, 36);
    CONS4(A, 32); LOAD4(A, 40);
    CONS4(B, 36); LOAD4(B, 44);
    CONS4(A, 40); LOAD4(A, 48);
    CONS4(B, 44); LOAD4(B, 52);
    CONS4(A, 48); LOAD4(A, 56);
    CONS4(B, 52); LOAD4(B, 60);
    CONS4(A, 56); LOAD4(A, 64);
    CONS4(B, 60); LOAD4(B, 68);
    CONS4(A, 64); LOAD4(A, 72);
    CONS4(B, 68); LOAD4(B, 76);
    CONS4(A, 72); LOAD4(A, 80);
    CONS4(B, 76); LOAD4(B, 84);
    CONS4(A, 80); LOAD4(A, 88);
    CONS4(B, 84); LOAD4(B, 92);
    CONS4(A, 88); LOAD4(A, 96);
    CONS4(B, 92);
    CONS4(A, 96);                       // t=96..99 -> word 3, bits 0..3
#undef LOAD4
#undef CONS4

    uint32_t* sp = spk + ((size_t)slab << 17);   // slab stride = 4*HWC u32
#pragma unroll
    for (int tw = 0; tw < 4; ++tw) {
        uint4 o; o.x = w[tw][0]; o.y = w[tw][1]; o.z = w[tw][2]; o.w = w[tw][3];
        *(uint4*)(sp + (size_t)tw * HWC + n0) = o;
    }
}

// ---------------- K2: bit expand + transpose (proven round-0 kernel) -------
__global__ __launch_bounds__(512) void expand_bits(const uint32_t* __restrict__ spk,
                                                   float* __restrict__ out) {
    __shared__ uint32_t lds[2 * 2112];           // 2 planes x 64h x 33 (pad)
    unsigned gid  = blockIdx.x;                  // [0, 512)
    unsigned slab = gid >> 6;
    unsigned q    = (gid >> 4) & 3u;
    unsigned tile = gid & 15u;
    unsigned wc0  = tile * 32u;
    unsigned t0   = q * 25u;
    unsigned p0   = t0 >> 5;                     // first bit-plane (0,0,1,2)
    unsigned p1   = (t0 + 24u) >> 5;             // second bit-plane (0,1,2,3)
    unsigned tid  = threadIdx.x;

    const uint32_t* sbase = spk + ((size_t)slab << 17);
#pragma unroll
    for (int it = 0; it < 8; ++it) {
        unsigned idx = it * 512u + tid;          // [0, 4096)
        unsigned pl  = idx >> 11;                // 0 / 1
        unsigned r   = idx & 2047u;
        unsigned h   = r >> 5, wcl = r & 31u;
        unsigned tw  = pl ? p1 : p0;
        lds[pl * 2112u + h * 33u + wcl] =
            sbase[((size_t)tw << 15) + h * 512u + wc0 + wcl];
    }
    __syncthreads();

    unsigned wcl = tid >> 4;                     // [0, 32)
    unsigned h0  = (tid & 15u) * 4u;             // 0,4,...,60
    uint32_t r0[4], r1[4];
#pragma unroll
    for (int k = 0; k < 4; ++k) {                // 2-way bank aliasing (free)
        r0[k] = lds[(h0 + k) * 33u + wcl];
        r1[k] = lds[2112u + (h0 + k) * 33u + wcl];
    }

    unsigned b = slab >> 1, ch = slab & 1u;
    unsigned rbase = b * TTOT + ch * CHUNK;      // output region index base
    float4* o4 = (float4*)out;

#pragma unroll
    for (int j = 0; j < 25; ++j) {
        unsigned t   = t0 + j;
        unsigned sel = (t >> 5) != p0;           // wave-uniform
        unsigned bit = t & 31u;
        uint32_t a0 = sel ? r1[0] : r0[0];
        uint32_t a1 = sel ? r1[1] : r0[1];
        uint32_t a2 = sel ? r1[2] : r0[2];
        uint32_t a3 = sel ? r1[3] : r0[3];
        float4 v;
        v.x = (float)((a0 >> bit) & 1u);
        v.y = (float)((a1 >> bit) & 1u);
        v.z = (float)((a2 >> bit) & 1u);
        v.w = (float)((a3 >> bit) & 1u);
        o4[(size_t)(rbase + t) * 8192u + wc0 * 16u + tid] = v;
    }
}

// ---------------- Fallback (ws too small): in-place scheme -----------------
__global__ __launch_bounds__(256) void spike_kernel_ip(const float* __restrict__ x,
                                                       uint8_t* __restrict__ spk) {
    unsigned g     = blockIdx.x * 256u + threadIdx.x;
    unsigned chunk = g >> 16;
    unsigned p     = g & 65535u;
    unsigned b     = p >> 14;
    unsigned i     = (p & 16383u) * 2u;
    unsigned t0    = b * TTOT + chunk * CHUNK;
    const float2* xp = (const float2*)(x + (size_t)t0 * HWC + i);
    uint8_t*      sp = spk + (size_t)t0 * 131072u + i;
    float a0 = 0.0f, a1 = 0.0f;
    for (int tb = 0; tb < CHUNK; tb += 4) {
        float2 v[4];
#pragma unroll
        for (int k = 0; k < 4; ++k) v[k] = xp[(size_t)k * (HWC / 2)];
        xp += 4 * (HWC / 2);
#pragma unroll
        for (int k = 0; k < 4; ++k) {
            a0 += v[k].x; a1 += v[k].y;
            unsigned s0 = 0u, s1 = 0u;
            if (a0 > 2.0f) { s0 = 1u; a0 = 0.0f; }
            if (a1 > 2.0f) { s1 = 1u; a1 = 0.0f; }
            *(uint16_t*)sp = (uint16_t)(s0 | (s1 << 8));
            sp += 131072u;
        }
    }
}

__global__ __launch_bounds__(512) void transpose_ip(float* __restrict__ out) {
    __shared__ uint32_t lds[64 * 129];
    unsigned region = blockIdx.x;
    unsigned tid = threadIdx.x;
    const uint32_t* in32 = (const uint32_t*)((const uint8_t*)out + (size_t)region * 131072u);
#pragma unroll
    for (int it = 0; it < 16; ++it) {
        unsigned idx = it * 512u + tid;
        unsigned h = idx >> 7, wq = idx & 127u;
        lds[h * 129u + wq] = in32[idx];
    }
    __syncthreads();
    float4* out4 = (float4*)out + (size_t)region * 8192u;
#pragma unroll
    for (int it = 0; it < 16; ++it) {
        unsigned f  = it * 512u + tid;
        unsigned wc = f >> 4;
        unsigned h0 = (f & 15u) << 2;
        unsigned wq = wc >> 2, sel = (wc & 3u) * 8u;
        float4 v;
        v.x = (float)((lds[(h0 + 0u) * 129u + wq] >> sel) & 1u);
        v.y = (float)((lds[(h0 + 1u) * 129u + wq] >> sel) & 1u);
        v.z = (float)((lds[(h0 + 2u) * 129u + wq] >> sel) & 1u);
        v.w = (float)((lds[(h0 + 3u) * 129u + wq] >> sel) & 1u);
        out4[f] = v;
    }
}

extern "C" void kernel_launch(void* const* d_in, const int* in_sizes, int n_in,
                              void* d_out, int out_size, void* d_ws, size_t ws_size,
                              hipStream_t stream) {
    (void)in_sizes; (void)n_in; (void)out_size;
    const float* x = (const float*)d_in[0];
    float* out = (float*)d_out;

    const size_t bit_bytes = (size_t)NSLAB * 4u * HWC * 4u;   // 4 MB
    if (ws_size >= bit_bytes) {
        uint32_t* spk = (uint32_t*)d_ws;
        hipLaunchKernelGGL(spike_bits4, dim3(256), dim3(256), 0, stream, x, spk);
        hipLaunchKernelGGL(expand_bits, dim3(512), dim3(512), 0, stream, spk, out);
    } else {
        hipLaunchKernelGGL(spike_kernel_ip, dim3(512), dim3(256), 0, stream, x, (uint8_t*)out);
        hipLaunchKernelGGL(transpose_ip, dim3(NSLAB * CHUNK), dim3(512), 0, stream, out);
    }
}

// Round 5
// 182.174 us; speedup vs baseline: 1.0020x; 1.0020x over previous
//
#include <hip/hip_runtime.h>
#include <stdint.h>

// Input  x[b,t,h,w,c] : (4, 200, 64, 64, 8) fp32, n = h*512 + wc (wc = w*8+c)
// Output out[b,t,w,c,h]: (4, 200, 64, 8, 64) fp32
// Per neuron, per 100-step chunk: acc += x[t]; if (acc > 2) { spike=1; acc=0; }
//
// K1 spike_bits_async: async-LDS pipelined scan. The key fix: previous rounds'
//   register double-buffers were COLLAPSED by the compiler (round-2 VGPR=32 vs
//   32 regs of buffer in source), leaving ~2-4 loads in flight -> 2.9 TB/s.
//   global_load_lds + counted "s_waitcnt vmcnt(19)" gives a hardware-
//   guaranteed 20-plane window (5 KB/wave, 80 KB/CU in flight), wave-private
//   LDS slots (no barriers). 1024 blocks x 256 thr, 1 neuron/thread.
// K2 expand_bits: UNCHANGED (control) - write-optimal round-0 kernel.
#define HWC    32768
#define NSLAB  8
#define TTOT   200
#define CHUNK  100

// ---------------- K1: async bit-packed integrate-and-fire scan -------------
__global__ __launch_bounds__(256) void spike_bits_async(const float* __restrict__ x,
                                                        uint32_t* __restrict__ spk) {
    // [slot 0..19][wave 0..3][lane 0..63] floats = 20 KB
    __shared__ float lds[20 * 256];

    unsigned g    = blockIdx.x * 256u + threadIdx.x;   // [0, 262144)
    unsigned slab = g >> 15;                           // [0, 8)
    unsigned n    = g & 32767u;
    unsigned b    = slab >> 1, ch = slab & 1u;
    const float* xb = x + (size_t)(b * TTOT + ch * CHUNK) * HWC + n;

    unsigned lane = threadIdx.x & 63u;
    float*   lw   = &lds[(threadIdx.x >> 6) * 64u];    // wave-uniform base

    float acc = 0.0f;
    uint32_t w[4] = {0u, 0u, 0u, 0u};

    // Fire-and-forget global->LDS: per-lane global src (xb is per-lane),
    // wave-uniform LDS dest + lane*4 (HW rule). 1 instr = 256 B/wave.
#define GL(T, SLOT)                                                        \
    __builtin_amdgcn_global_load_lds(                                      \
        (const __attribute__((address_space(1))) void*)(xb + (size_t)(T) * HWC), \
        (__attribute__((address_space(3))) void*)(lw + (SLOT) * 256u),     \
        4, 0, 0)

    // Consume plane T from slot SLOT once <=VN older loads may be in flight.
#define STC(T, SLOT, VN)                                                   \
    do {                                                                   \
        asm volatile("s_waitcnt vmcnt(" #VN ")" ::: "memory");             \
        __builtin_amdgcn_sched_barrier(0);                                 \
        float v = lw[(SLOT) * 256u + lane];                                \
        acc += v;                                                          \
        if (acc > 2.0f) { w[(T) >> 5] |= (1u << ((T) & 31)); acc = 0.0f; } \
    } while (0)

    // Steady state: consume plane T, then refill its slot with plane T+20.
#define ST(T, SLOT) do { STC(T, SLOT, 19); GL((T) + 20, SLOT); } while (0)
#define ROW5(T0, S0) ST(T0, S0); ST((T0)+1, (S0)+1); ST((T0)+2, (S0)+2); \
                     ST((T0)+3, (S0)+3); ST((T0)+4, (S0)+4)
#define ROW20(T0) ROW5(T0, 0); ROW5((T0)+5, 5); ROW5((T0)+10, 10); ROW5((T0)+15, 15)

    // Prologue: fill all 20 slots (planes 0..19).
#pragma unroll
    for (int t = 0; t < 20; ++t) GL(t, t);

    // Main: planes 0..79 with refill (planes 20..99 issued here).
    ROW20(0); ROW20(20); ROW20(40); ROW20(60);

    // Drain: planes 80..99, vmcnt literal descending 19..0.
    STC(80,  0, 19); STC(81,  1, 18); STC(82,  2, 17); STC(83,  3, 16);
    STC(84,  4, 15); STC(85,  5, 14); STC(86,  6, 13); STC(87,  7, 12);
    STC(88,  8, 11); STC(89,  9, 10); STC(90, 10,  9); STC(91, 11,  8);
    STC(92, 12,  7); STC(93, 13,  6); STC(94, 14,  5); STC(95, 15,  4);
    STC(96, 16,  3); STC(97, 17,  2); STC(98, 18,  1); STC(99, 19,  0);

#undef ROW20
#undef ROW5
#undef ST
#undef STC
#undef GL

    // Store 4 bit-words: per tw, wave writes 256 B contiguous.
    uint32_t* sp = spk + ((size_t)slab << 17) + n;     // [slab][tw][n]
    sp[0]            = w[0];
    sp[HWC]          = w[1];
    sp[2u * HWC]     = w[2];
    sp[3u * HWC]     = w[3];
}

// ---------------- K2: bit expand + transpose (unchanged control) -----------
__global__ __launch_bounds__(512) void expand_bits(const uint32_t* __restrict__ spk,
                                                   float* __restrict__ out) {
    __shared__ uint32_t lds[2 * 2112];           // 2 planes x 64h x 33 (pad)
    unsigned gid  = blockIdx.x;                  // [0, 512)
    unsigned slab = gid >> 6;
    unsigned q    = (gid >> 4) & 3u;
    unsigned tile = gid & 15u;
    unsigned wc0  = tile * 32u;
    unsigned t0   = q * 25u;
    unsigned p0   = t0 >> 5;                     // first bit-plane (0,0,1,2)
    unsigned p1   = (t0 + 24u) >> 5;             // second bit-plane (0,1,2,3)
    unsigned tid  = threadIdx.x;

    const uint32_t* sbase = spk + ((size_t)slab << 17);
#pragma unroll
    for (int it = 0; it < 8; ++it) {
        unsigned idx = it * 512u + tid;          // [0, 4096)
        unsigned pl  = idx >> 11;                // 0 / 1
        unsigned r   = idx & 2047u;
        unsigned h   = r >> 5, wcl = r & 31u;
        unsigned tw  = pl ? p1 : p0;
        lds[pl * 2112u + h * 33u + wcl] =
            sbase[((size_t)tw << 15) + h * 512u + wc0 + wcl];
    }
    __syncthreads();

    unsigned wcl = tid >> 4;                     // [0, 32)
    unsigned h0  = (tid & 15u) * 4u;             // 0,4,...,60
    uint32_t r0[4], r1[4];
#pragma unroll
    for (int k = 0; k < 4; ++k) {                // 2-way bank aliasing (free)
        r0[k] = lds[(h0 + k) * 33u + wcl];
        r1[k] = lds[2112u + (h0 + k) * 33u + wcl];
    }

    unsigned b = slab >> 1, ch = slab & 1u;
    unsigned rbase = b * TTOT + ch * CHUNK;      // output region index base
    float4* o4 = (float4*)out;

#pragma unroll
    for (int j = 0; j < 25; ++j) {
        unsigned t   = t0 + j;
        unsigned sel = (t >> 5) != p0;           // wave-uniform
        unsigned bit = t & 31u;
        uint32_t a0 = sel ? r1[0] : r0[0];
        uint32_t a1 = sel ? r1[1] : r0[1];
        uint32_t a2 = sel ? r1[2] : r0[2];
        uint32_t a3 = sel ? r1[3] : r0[3];
        float4 v;
        v.x = (float)((a0 >> bit) & 1u);
        v.y = (float)((a1 >> bit) & 1u);
        v.z = (float)((a2 >> bit) & 1u);
        v.w = (float)((a3 >> bit) & 1u);
        o4[(size_t)(rbase + t) * 8192u + wc0 * 16u + tid] = v;
    }
}

// ---------------- Fallback (ws too small): in-place scheme -----------------
__global__ __launch_bounds__(256) void spike_kernel_ip(const float* __restrict__ x,
                                                       uint8_t* __restrict__ spk) {
    unsigned g     = blockIdx.x * 256u + threadIdx.x;
    unsigned chunk = g >> 16;
    unsigned p     = g & 65535u;
    unsigned b     = p >> 14;
    unsigned i     = (p & 16383u) * 2u;
    unsigned t0    = b * TTOT + chunk * CHUNK;
    const float2* xp = (const float2*)(x + (size_t)t0 * HWC + i);
    uint8_t*      sp = spk + (size_t)t0 * 131072u + i;
    float a0 = 0.0f, a1 = 0.0f;
    for (int tb = 0; tb < CHUNK; tb += 4) {
        float2 v[4];
#pragma unroll
        for (int k = 0; k < 4; ++k) v[k] = xp[(size_t)k * (HWC / 2)];
        xp += 4 * (HWC / 2);
#pragma unroll
        for (int k = 0; k < 4; ++k) {
            a0 += v[k].x; a1 += v[k].y;
            unsigned s0 = 0u, s1 = 0u;
            if (a0 > 2.0f) { s0 = 1u; a0 = 0.0f; }
            if (a1 > 2.0f) { s1 = 1u; a1 = 0.0f; }
            *(uint16_t*)sp = (uint16_t)(s0 | (s1 << 8));
            sp += 131072u;
        }
    }
}

__global__ __launch_bounds__(512) void transpose_ip(float* __restrict__ out) {
    __shared__ uint32_t lds[64 * 129];
    unsigned region = blockIdx.x;
    unsigned tid = threadIdx.x;
    const uint32_t* in32 = (const uint32_t*)((const uint8_t*)out + (size_t)region * 131072u);
#pragma unroll
    for (int it = 0; it < 16; ++it) {
        unsigned idx = it * 512u + tid;
        unsigned h = idx >> 7, wq = idx & 127u;
        lds[h * 129u + wq] = in32[idx];
    }
    __syncthreads();
    float4* out4 = (float4*)out + (size_t)region * 8192u;
#pragma unroll
    for (int it = 0; it < 16; ++it) {
        unsigned f  = it * 512u + tid;
        unsigned wc = f >> 4;
        unsigned h0 = (f & 15u) << 2;
        unsigned wq = wc >> 2, sel = (wc & 3u) * 8u;
        float4 v;
        v.x = (float)((lds[(h0 + 0u) * 129u + wq] >> sel) & 1u);
        v.y = (float)((lds[(h0 + 1u) * 129u + wq] >> sel) & 1u);
        v.z = (float)((lds[(h0 + 2u) * 129u + wq] >> sel) & 1u);
        v.w = (float)((lds[(h0 + 3u) * 129u + wq] >> sel) & 1u);
        out4[f] = v;
    }
}

extern "C" void kernel_launch(void* const* d_in, const int* in_sizes, int n_in,
                              void* d_out, int out_size, void* d_ws, size_t ws_size,
                              hipStream_t stream) {
    (void)in_sizes; (void)n_in; (void)out_size;
    const float* x = (const float*)d_in[0];
    float* out = (float*)d_out;

    const size_t bit_bytes = (size_t)NSLAB * 4u * HWC * 4u;   // 4 MB
    if (ws_size >= bit_bytes) {
        uint32_t* spk = (uint32_t*)d_ws;
        hipLaunchKernelGGL(spike_bits_async, dim3(1024), dim3(256), 0, stream, x, spk);
        hipLaunchKernelGGL(expand_bits, dim3(512), dim3(512), 0, stream, spk, out);
    } else {
        hipLaunchKernelGGL(spike_kernel_ip, dim3(512), dim3(256), 0, stream, x, (uint8_t*)out);
        hipLaunchKernelGGL(transpose_ip, dim3(NSLAB * CHUNK), dim3(512), 0, stream, out);
    }
}